// Round 9
// baseline (205.787 us; speedup 1.0000x reference)
//
#include <hip/hip_runtime.h>
#include <math.h>

#define B 32
#define C 256
#define M 64
#define N 4096  // H*W

typedef __attribute__((ext_vector_type(8))) short s16x8;
typedef __attribute__((ext_vector_type(8))) __bf16 bf16x8;
typedef __attribute__((ext_vector_type(4))) __bf16 bf16x4;
typedef __attribute__((ext_vector_type(4))) float f32x4;
typedef __attribute__((ext_vector_type(4))) unsigned short u16x4;
typedef __attribute__((ext_vector_type(8))) unsigned short u16x8;

static constexpr float EPS = 1e-12f;

__device__ __forceinline__ float bf2f(unsigned short h) {
    return __uint_as_float((unsigned)h << 16);
}
__device__ __forceinline__ f32x4 MFMA(s16x8 a, s16x8 b, f32x4 c) {
    return __builtin_amdgcn_mfma_f32_16x16x32_bf16(
        __builtin_bit_cast(bf16x8, a), __builtin_bit_cast(bf16x8, b), c, 0, 0, 0);
}
__device__ __forceinline__ s16x8 cvt8(const f32x4 a, const f32x4 b) {
    bf16x8 h;
    h[0] = (__bf16)a[0]; h[1] = (__bf16)a[1]; h[2] = (__bf16)a[2]; h[3] = (__bf16)a[3];
    h[4] = (__bf16)b[0]; h[5] = (__bf16)b[1]; h[6] = (__bf16)b[2]; h[7] = (__bf16)b[3];
    return __builtin_bit_cast(s16x8, h);
}
// bank-injective LDS swizzle for the 32x256-hw tile: flips hw bits 4-5 by n>>2
__device__ __forceinline__ int fsw(int n) {
    return ((n >> 2) & 3) << 4;
}

// ---------------------------------------------------------------------------
// K01: fused convert + transpose + logits. 32n x 256c tile, 16.9 KB LDS
// (8 blocks/CU), conflict-free swizzle, all loads issued before use.
// ---------------------------------------------------------------------------
__global__ __launch_bounds__(256) void k01(const float* __restrict__ x,
                                           const float* __restrict__ Wf,
                                           unsigned short* __restrict__ xbt,
                                           unsigned short* __restrict__ Sb,
                                           float* __restrict__ xsq) {
    const int nb = blockIdx.x, b = blockIdx.y;  // nb: 32-n tile index
    const int t = threadIdx.x;
    __shared__ unsigned short tsT[32 * 256];  // [n][c^fsw(n)] bf16
    __shared__ float red[4][32];
    const int wave = t >> 6, lane = t & 63;
    // ---- phase A: load 8 f32x4 (4c x 4n x 2 steps), cvt, swizzled LDS ----
    const int nq = t & 7, cp = t >> 3;
    const float* xrow = x + (size_t)b * C * N + (size_t)nb * 32 + 4 * nq;
    f32x4 q[8];
#pragma unroll
    for (int step = 0; step < 2; ++step)
#pragma unroll
        for (int i = 0; i < 4; ++i)
            q[step * 4 + i] = *(const f32x4*)(xrow + (size_t)(cp * 4 + step * 128 + i) * N);
    float part[4] = {0.f, 0.f, 0.f, 0.f};
#pragma unroll
    for (int step = 0; step < 2; ++step) {
        const int c0 = cp * 4 + step * 128;
#pragma unroll
        for (int k = 0; k < 4; ++k) {
            const int n = 4 * nq + k;
            bf16x4 hb;
#pragma unroll
            for (int i = 0; i < 4; ++i) {
                part[k] += q[step * 4 + i][k] * q[step * 4 + i][k];
                hb[i] = (__bf16)q[step * 4 + i][k];
            }
            *(u16x4*)(&tsT[n * 256 + (c0 ^ fsw(n))]) = __builtin_bit_cast(u16x4, hb);
        }
    }
    // in-wave reduce part[] over cp (lanes 8,16,32 apart), stash per-wave
#pragma unroll
    for (int k = 0; k < 4; ++k) {
        part[k] += __shfl_xor(part[k], 8);
        part[k] += __shfl_xor(part[k], 16);
        part[k] += __shfl_xor(part[k], 32);
    }
    if (lane < 8) {
#pragma unroll
        for (int k = 0; k < 4; ++k) red[wave][4 * lane + k] = part[k];
    }
    __syncthreads();
    if (t < 32)
        xsq[(size_t)b * N + nb * 32 + t] =
            red[0][t] + red[1][t] + red[2][t] + red[3][t];
    // ---- phase B1: xbt coalesced write ----
    {
        const int l = t & 31, r = t >> 5;
#pragma unroll
        for (int j = 0; j < 4; ++j) {
            const int n = r + 8 * j;
            const int c0 = l * 8;
            const u16x8 v = *(const u16x8*)(&tsT[n * 256 + (c0 ^ fsw(n))]);
            *(u16x8*)(xbt + ((size_t)b * N + nb * 32 + n) * C + c0) = v;
        }
    }
    // ---- phase B2: logits MFMA. wave -> (n-half s, m-half mh) ----
    const int li = lane & 15, lk = lane >> 4;
    const int s = wave >> 1, mh = (wave & 1) * 32;
    const f32x4 zv = {0.f, 0.f, 0.f, 0.f};
    f32x4 acc[2] = {zv, zv};
    const int an = s * 16 + li;
#pragma unroll
    for (int c0 = 0; c0 < C; c0 += 32) {
        const s16x8 a = *(const s16x8*)(&tsT[an * 256 + ((lk * 8 + c0) ^ fsw(an))]);
#pragma unroll
        for (int u = 0; u < 2; ++u) {
            const float* wr = Wf + (size_t)(mh + u * 16 + li) * C + c0 + lk * 8;
            const s16x8 bf_ = cvt8(*(const f32x4*)wr, *(const f32x4*)(wr + 4));
            acc[u] = MFMA(a, bf_, acc[u]);
        }
    }
#pragma unroll
    for (int u = 0; u < 2; ++u) {
        bf16x4 h;
#pragma unroll
        for (int r = 0; r < 4; ++r) h[r] = (__bf16)acc[u][r];
        *(u16x4*)(Sb + ((size_t)b * M + mh + u * 16 + li) * N + nb * 32 + s * 16 + lk * 4) =
            __builtin_bit_cast(u16x4, h);
    }
}

// ---------------------------------------------------------------------------
// K2: softmax over n per (b,m); bf16 in -> bf16 out.
// ---------------------------------------------------------------------------
__global__ __launch_bounds__(256) void k2_softmax_n(const unsigned short* __restrict__ Sb,
                                                    unsigned short* __restrict__ Pb) {
    const int m = blockIdx.x, b = blockIdx.y;
    const unsigned short* col = Sb + ((size_t)b * M + m) * N;
    unsigned short* po = Pb + ((size_t)b * M + m) * N;
    const int t = threadIdx.x;
    float v[16];
    const u16x8 h0 = *(const u16x8*)(col + t * 16);
    const u16x8 h1 = *(const u16x8*)(col + t * 16 + 8);
#pragma unroll
    for (int i = 0; i < 8; ++i) v[i] = bf2f(h0[i]);
#pragma unroll
    for (int i = 0; i < 8; ++i) v[8 + i] = bf2f(h1[i]);
    float mx = -INFINITY;
#pragma unroll
    for (int i = 0; i < 16; ++i) mx = fmaxf(mx, v[i]);
#pragma unroll
    for (int off = 32; off >= 1; off >>= 1) mx = fmaxf(mx, __shfl_xor(mx, off));
    __shared__ float redm[4], reds[4];
    const int wave = t >> 6, lane = t & 63;
    if (lane == 0) redm[wave] = mx;
    __syncthreads();
    mx = fmaxf(fmaxf(redm[0], redm[1]), fmaxf(redm[2], redm[3]));
    float s = 0.f;
#pragma unroll
    for (int i = 0; i < 16; ++i) {
        v[i] = __expf(v[i] - mx);
        s += v[i];
    }
#pragma unroll
    for (int off = 32; off >= 1; off >>= 1) s += __shfl_xor(s, off);
    if (lane == 0) reds[wave] = s;
    __syncthreads();
    s = reds[0] + reds[1] + reds[2] + reds[3];
    const float inv = 1.f / s;
    bf16x8 o0, o1;
#pragma unroll
    for (int i = 0; i < 8; ++i) o0[i] = (__bf16)(v[i] * inv);
#pragma unroll
    for (int i = 0; i < 8; ++i) o1[i] = (__bf16)(v[8 + i] * inv);
    *(u16x8*)(po + t * 16) = __builtin_bit_cast(u16x8, o0);
    *(u16x8*)(po + t * 16 + 8) = __builtin_bit_cast(u16x8, o1);
}

// ---------------------------------------------------------------------------
// K3: proto partials parts[b][ck][m][c] over 512-n chunks. (verified)
// ---------------------------------------------------------------------------
__global__ __launch_bounds__(256) void k3_mfma(const float* __restrict__ x,
                                               const unsigned short* __restrict__ Pb,
                                               float* __restrict__ parts) {
    const int ck = blockIdx.x, b = blockIdx.y;
    const int wv = threadIdx.x >> 6, lane = threadIdx.x & 63;
    const int li = lane & 15, lk = lane >> 4;
    const int c0w = wv * 64;
    const int nb = ck * 512;
    const f32x4 zv = {0.f, 0.f, 0.f, 0.f};
    f32x4 acc[4][4];
#pragma unroll
    for (int s = 0; s < 4; ++s)
#pragma unroll
        for (int u = 0; u < 4; ++u) acc[s][u] = zv;
    const float* ar = x + ((size_t)b * C + c0w + li) * N + nb + lk * 8;
    const unsigned short* br = Pb + ((size_t)b * M + li) * N + nb + lk * 8;
#pragma unroll 4
    for (int n0 = 0; n0 < 512; n0 += 32) {
        s16x8 af[4], bf_[4];
#pragma unroll
        for (int s = 0; s < 4; ++s) {
            const float* p = ar + (size_t)(s * 16) * N + n0;
            af[s] = cvt8(*(const f32x4*)p, *(const f32x4*)(p + 4));
        }
#pragma unroll
        for (int u = 0; u < 4; ++u) bf_[u] = *(const s16x8*)(br + (size_t)(u * 16) * N + n0);
#pragma unroll
        for (int s = 0; s < 4; ++s)
#pragma unroll
            for (int u = 0; u < 4; ++u) acc[s][u] = MFMA(af[s], bf_[u], acc[s][u]);
    }
    float* pp = parts + ((size_t)b * 8 + ck) * M * C;
#pragma unroll
    for (int s = 0; s < 4; ++s)
#pragma unroll
        for (int u = 0; u < 4; ++u)
            *(f32x4*)(pp + (size_t)(u * 16 + li) * C + c0w + s * 16 + lk * 4) = acc[s][u];
}

// ---------------------------------------------------------------------------
// K3b: reduce 8 chunks -> l2norm -> proto_bf [m][c], protoT_bf [c][m], p2.
// ---------------------------------------------------------------------------
__global__ __launch_bounds__(256) void k3b_reduce(const float* __restrict__ parts,
                                                  unsigned short* __restrict__ proto_bf,
                                                  unsigned short* __restrict__ protoT_bf,
                                                  float* __restrict__ p2) {
    const int mb = blockIdx.x, b = blockIdx.y;
    const int t = threadIdx.x;
    const int ml = t >> 5, cl = t & 31;
    const int m = mb * 8 + ml;
    const int c0 = cl * 8;
    float v[8] = {0.f, 0.f, 0.f, 0.f, 0.f, 0.f, 0.f, 0.f};
    const float* pbase = parts + (size_t)b * 8 * M * C + (size_t)m * C + c0;
#pragma unroll
    for (int ck = 0; ck < 8; ++ck) {
        const f32x4 q0 = *(const f32x4*)(pbase + (size_t)ck * M * C);
        const f32x4 q1 = *(const f32x4*)(pbase + (size_t)ck * M * C + 4);
#pragma unroll
        for (int j = 0; j < 4; ++j) { v[j] += q0[j]; v[4 + j] += q1[j]; }
    }
    float sq = 0.f;
#pragma unroll
    for (int j = 0; j < 8; ++j) sq += v[j] * v[j];
#pragma unroll
    for (int off = 16; off >= 1; off >>= 1) sq += __shfl_xor(sq, off);
    const float denom = fmaxf(sqrtf(sq), EPS);
    const float scale = 1.f / denom;
    if (cl == 0) p2[b * M + m] = sq / (denom * denom);
    bf16x8 h;
#pragma unroll
    for (int j = 0; j < 8; ++j) h[j] = (__bf16)(v[j] * scale);
    const u16x8 hu = __builtin_bit_cast(u16x8, h);
    *(u16x8*)(proto_bf + ((size_t)b * M + m) * C + c0) = hu;
#pragma unroll
    for (int j = 0; j < 8; ++j)
        protoT_bf[((size_t)b * C + c0 + j) * M + m] = hu[j];
}

// ---------------------------------------------------------------------------
// K4: score + softmax-m (unnormalized; 1/sum cancels in L2-norm) + compact
// partials -> pnm bf16 [b][n][m].
// ---------------------------------------------------------------------------
__global__ __launch_bounds__(256) void k4_score(const unsigned short* __restrict__ proto_bf,
                                                const unsigned short* __restrict__ xbt,
                                                const float* __restrict__ p2,
                                                const float* __restrict__ xsq,
                                                unsigned short* __restrict__ pnm,
                                                float* __restrict__ cparts) {
    const int b = blockIdx.y;
    const int wv = threadIdx.x >> 6, lane = threadIdx.x & 63;
    const int li = lane & 15, lk = lane >> 4;
    const int nbase = blockIdx.x * 256 + wv * 64;
    const f32x4 zv = {0.f, 0.f, 0.f, 0.f};
    f32x4 acc[4][4];
#pragma unroll
    for (int s = 0; s < 4; ++s)
#pragma unroll
        for (int u = 0; u < 4; ++u) acc[s][u] = zv;
    const unsigned short* ar = proto_bf + ((size_t)b * M + li) * C + lk * 8;
    const unsigned short* br = xbt + ((size_t)b * N + nbase + li) * C + lk * 8;
#pragma unroll
    for (int c0 = 0; c0 < C; c0 += 32) {
        s16x8 af[4], bf_[4];
#pragma unroll
        for (int s = 0; s < 4; ++s) af[s] = *(const s16x8*)(ar + (size_t)(s * 16) * C + c0);
#pragma unroll
        for (int u = 0; u < 4; ++u) bf_[u] = *(const s16x8*)(br + (size_t)(u * 16) * C + c0);
#pragma unroll
        for (int s = 0; s < 4; ++s)
#pragma unroll
            for (int u = 0; u < 4; ++u) acc[s][u] = MFMA(af[s], bf_[u], acc[s][u]);
    }
    float csum = 0.f;
#pragma unroll
    for (int u = 0; u < 4; ++u) {
        const int n = nbase + u * 16 + li;
        float vmax = -INFINITY;
#pragma unroll
        for (int s = 0; s < 4; ++s)
#pragma unroll
            for (int r = 0; r < 4; ++r) vmax = fmaxf(vmax, acc[s][u][r]);
        vmax = fmaxf(vmax, __shfl_xor(vmax, 16));
        vmax = fmaxf(vmax, __shfl_xor(vmax, 32));
        int t1 = 1 << 30;
#pragma unroll
        for (int s = 0; s < 4; ++s)
#pragma unroll
            for (int r = 0; r < 4; ++r)
                if (acc[s][u][r] == vmax) t1 = min(t1, s * 16 + lk * 4 + r);
        t1 = min(t1, __shfl_xor(t1, 16));
        t1 = min(t1, __shfl_xor(t1, 32));
        unsigned short* prow = pnm + ((size_t)b * N + n) * M;
#pragma unroll
        for (int s = 0; s < 4; ++s) {
            bf16x4 h;
#pragma unroll
            for (int r = 0; r < 4; ++r) h[r] = (__bf16)__expf(acc[s][u][r] - vmax);
            *(u16x4*)(prow + s * 16 + lk * 4) = __builtin_bit_cast(u16x4, h);
        }
        if (lk == 0) csum += xsq[(size_t)b * N + n] - 2.f * vmax + p2[b * M + t1];
    }
#pragma unroll
    for (int off = 32; off >= 1; off >>= 1) csum += __shfl_xor(csum, off);
    __shared__ float red[4];
    if (lane == 0) red[wv] = csum;
    __syncthreads();
    if (threadIdx.x == 0)
        cparts[b * 16 + blockIdx.x] = red[0] + red[1] + red[2] + red[3];
}

// ---------------------------------------------------------------------------
// K4b: out = l2norm_c(sum_m p[n][m]*protoT[c][m]).
// ---------------------------------------------------------------------------
__global__ __launch_bounds__(256) void k4b_mfma(const unsigned short* __restrict__ pnm,
                                                const unsigned short* __restrict__ protoT_bf,
                                                float* __restrict__ out) {
    const int b = blockIdx.y;
    const int wv = threadIdx.x >> 6, lane = threadIdx.x & 63;
    const int li = lane & 15, lk = lane >> 4;
    const int n0 = blockIdx.x * 64;
    const int cb = wv * 64;
    const f32x4 zv = {0.f, 0.f, 0.f, 0.f};
    f32x4 acc[4][4];
#pragma unroll
    for (int s = 0; s < 4; ++s)
#pragma unroll
        for (int u = 0; u < 4; ++u) acc[s][u] = zv;
    const unsigned short* ar = pnm + ((size_t)b * N + n0 + li) * M + lk * 8;
    const unsigned short* br = protoT_bf + ((size_t)b * C + cb + li) * M + lk * 8;
#pragma unroll
    for (int m0 = 0; m0 < M; m0 += 32) {
        s16x8 af[4], bf_[4];
#pragma unroll
        for (int s = 0; s < 4; ++s) af[s] = *(const s16x8*)(ar + (size_t)(s * 16) * M + m0);
#pragma unroll
        for (int u = 0; u < 4; ++u) bf_[u] = *(const s16x8*)(br + (size_t)(u * 16) * M + m0);
#pragma unroll
        for (int s = 0; s < 4; ++s)
#pragma unroll
            for (int u = 0; u < 4; ++u) acc[s][u] = MFMA(af[s], bf_[u], acc[s][u]);
    }
    __shared__ float ls[4][64];
    __shared__ float ls2[64];
    float psq[4][4];
#pragma unroll
    for (int s = 0; s < 4; ++s)
#pragma unroll
        for (int r = 0; r < 4; ++r) {
            float sum = 0.f;
#pragma unroll
            for (int u = 0; u < 4; ++u) sum += acc[s][u][r] * acc[s][u][r];
#pragma unroll
            for (int off = 8; off >= 1; off >>= 1) sum += __shfl_xor(sum, off);
            psq[s][r] = sum;
        }
    if (li == 0) {
#pragma unroll
        for (int s = 0; s < 4; ++s)
#pragma unroll
            for (int r = 0; r < 4; ++r) ls[wv][s * 16 + lk * 4 + r] = psq[s][r];
    }
    __syncthreads();
    if (threadIdx.x < 64) {
        const int tt = threadIdx.x;
        const float tot = ls[0][tt] + ls[1][tt] + ls[2][tt] + ls[3][tt];
        ls2[tt] = 1.f / fmaxf(sqrtf(tot), EPS);
    }
    __syncthreads();
    float scl[4][4];
#pragma unroll
    for (int s = 0; s < 4; ++s)
#pragma unroll
        for (int r = 0; r < 4; ++r) scl[s][r] = ls2[s * 16 + lk * 4 + r];
    float* ob = out + (size_t)b * C * N;
#pragma unroll
    for (int s = 0; s < 4; ++s)
#pragma unroll
        for (int u = 0; u < 4; ++u) {
            f32x4 q;
#pragma unroll
            for (int r = 0; r < 4; ++r) q[r] = acc[s][u][r] * scl[s][r];
            *(f32x4*)(ob + (size_t)(cb + u * 16 + li) * N + n0 + s * 16 + lk * 4) = q;
        }
}

// ---------------------------------------------------------------------------
// K5 / K6: losses.
// ---------------------------------------------------------------------------
__global__ __launch_bounds__(256) void k5_dis(const unsigned short* __restrict__ proto_bf,
                                              const float* __restrict__ p2,
                                              float* __restrict__ dparts) {
    const int q = blockIdx.x;
    const int b = blockIdx.y;
    const unsigned short* pr = proto_bf + (size_t)b * M * C;
    __shared__ float pl[M * C];
    for (int idx = threadIdx.x; idx < M * C; idx += 256) {
        int m = idx >> 8, c = idx & 255;
        pl[m * 256 + (c ^ (m & 31))] = bf2f(pr[idx]);
    }
    __syncthreads();
    float sum = 0.f;
    for (int k = 0; k < 2; ++k) {
        const int pair = q * 512 + k * 256 + threadIdx.x;
        const int i = pair >> 6, j = pair & 63;
        if (j > i) {
            float g = 0.f;
#pragma unroll 8
            for (int c = 0; c < C; ++c)
                g += pl[i * 256 + (c ^ (i & 31))] * pl[j * 256 + (c ^ (j & 31))];
            const float d = 1.f - (p2[b * M + i] + p2[b * M + j] - 2.f * g);
            sum += fmaxf(d, 0.f);
        }
    }
#pragma unroll
    for (int off = 32; off >= 1; off >>= 1) sum += __shfl_xor(sum, off);
    __shared__ float red[4];
    const int wave = threadIdx.x >> 6, lane = threadIdx.x & 63;
    if (lane == 0) red[wave] = sum;
    __syncthreads();
    if (threadIdx.x == 0) dparts[b * 8 + q] = red[0] + red[1] + red[2] + red[3];
}

__global__ __launch_bounds__(256) void k6_final(const float* __restrict__ cparts, int ncp,
                                                const float* __restrict__ dparts,
                                                float* __restrict__ losses) {
    const int t = threadIdx.x;
    float cs = 0.f;
    for (int i = t; i < ncp; i += 256) cs += cparts[i];
    float ds = dparts[t];
#pragma unroll
    for (int off = 32; off >= 1; off >>= 1) {
        cs += __shfl_xor(cs, off);
        ds += __shfl_xor(ds, off);
    }
    __shared__ float rc[4], rd[4];
    const int wave = t >> 6, lane = t & 63;
    if (lane == 0) { rc[wave] = cs; rd[wave] = ds; }
    __syncthreads();
    if (t == 0) {
        const float ctot = rc[0] + rc[1] + rc[2] + rc[3];
        const float dtot = rd[0] + rd[1] + rd[2] + rd[3];
        losses[0] = ctot / ((float)B * (float)N * (float)C);
        losses[1] = dtot * (2.f / (float)(M * (M - 1))) / (float)B;
    }
}

extern "C" void kernel_launch(void* const* d_in, const int* in_sizes, int n_in,
                              void* d_out, int out_size, void* d_ws, size_t ws_size,
                              hipStream_t stream) {
    const float* x = (const float*)d_in[0];
    const float* Wf = (const float*)d_in[1];
    float* out = (float*)d_out;
    float* wsf = (float*)d_ws;
    float* losses = out + (size_t)B * C * N;

    // Proven layout (r3/r4/r7): xbt in d_out (dead before k4b overwrites), rest in ws.
    unsigned short* xbt = (unsigned short*)d_out;
    unsigned short* Sbf = (unsigned short*)wsf;
    float* parts = wsf;
    unsigned short* Pbf = (unsigned short*)(wsf + 4194304);
    unsigned short* pnm = Pbf;
    float* xsq = wsf + 8388608;
    unsigned short* proto_bf = (unsigned short*)(wsf + 8519680);
    unsigned short* protoT_bf = (unsigned short*)(wsf + 8781824);
    float* p2 = wsf + 9052160;
    float* cparts = wsf + 9054208;
    float* dparts = wsf + 9054720;

    k01<<<dim3(N / 32, B), 256, 0, stream>>>(x, Wf, xbt, Sbf, xsq);
    k2_softmax_n<<<dim3(M, B), 256, 0, stream>>>(Sbf, Pbf);
    k3_mfma<<<dim3(8, B), 256, 0, stream>>>(x, Pbf, parts);
    k3b_reduce<<<dim3(8, B), 256, 0, stream>>>(parts, proto_bf, protoT_bf, p2);
    k4_score<<<dim3(N / 256, B), 256, 0, stream>>>(proto_bf, xbt, p2, xsq, pnm, cparts);
    k4b_mfma<<<dim3(N / 64, B), 256, 0, stream>>>(pnm, protoT_bf, out);
    k5_dis<<<dim3(8, B), 256, 0, stream>>>(proto_bf, p2, dparts);
    k6_final<<<1, 256, 0, stream>>>(cparts, B * 16, dparts, losses);
}

// Round 10
// 181.048 us; speedup vs baseline: 1.1366x; 1.1366x over previous
//
#include <hip/hip_runtime.h>
#include <math.h>

#define B 32
#define C 256
#define M 64
#define N 4096  // H*W

typedef __attribute__((ext_vector_type(8))) short s16x8;
typedef __attribute__((ext_vector_type(8))) __bf16 bf16x8;
typedef __attribute__((ext_vector_type(4))) __bf16 bf16x4;
typedef __attribute__((ext_vector_type(4))) float f32x4;
typedef __attribute__((ext_vector_type(4))) unsigned short u16x4;
typedef __attribute__((ext_vector_type(8))) unsigned short u16x8;

static constexpr float EPS = 1e-12f;

__device__ __forceinline__ float bf2f(unsigned short h) {
    return __uint_as_float((unsigned)h << 16);
}
__device__ __forceinline__ f32x4 MFMA(s16x8 a, s16x8 b, f32x4 c) {
    return __builtin_amdgcn_mfma_f32_16x16x32_bf16(
        __builtin_bit_cast(bf16x8, a), __builtin_bit_cast(bf16x8, b), c, 0, 0, 0);
}
__device__ __forceinline__ s16x8 cvt8(const f32x4 a, const f32x4 b) {
    bf16x8 h;
    h[0] = (__bf16)a[0]; h[1] = (__bf16)a[1]; h[2] = (__bf16)a[2]; h[3] = (__bf16)a[3];
    h[4] = (__bf16)b[0]; h[5] = (__bf16)b[1]; h[6] = (__bf16)b[2]; h[7] = (__bf16)b[3];
    return __builtin_bit_cast(s16x8, h);
}
// LDS column swizzle for the [n][c] bf16 tile (halfword units, flips bits 3-5 of c)
__device__ __forceinline__ int swz(int n) {
    return (((n >> 2) & 3) | ((n & 1) << 2)) << 3;
}

// ---------------------------------------------------------------------------
// K01: fused convert + transpose + logits (r7-proven version, 74.8us).
// 64n x 256c tile; W converted f32->bf16 in-reg; plain casts -> cvt_pk.
// ---------------------------------------------------------------------------
__global__ __launch_bounds__(256) void k01(const float* __restrict__ x,
                                           const float* __restrict__ Wf,
                                           unsigned short* __restrict__ xbt,
                                           unsigned short* __restrict__ Sb,
                                           float* __restrict__ xsq) {
    const int nb = blockIdx.x, b = blockIdx.y;
    const int t = threadIdx.x;
    __shared__ unsigned short tsT[64 * 256];
    __shared__ float xred[16][68];
    // ---- phase A: load 4c x 4n register blocks, cvt, stage to LDS ----
    const int nq = t & 15, cq = t >> 4;
    float part[4] = {0.f, 0.f, 0.f, 0.f};
    const float* xrow = x + (size_t)b * C * N + (size_t)nb * 64 + 4 * nq;
#pragma unroll
    for (int step = 0; step < 4; ++step) {
        const int c0 = cq * 4 + step * 64;
        f32x4 q[4];
#pragma unroll
        for (int i = 0; i < 4; ++i) q[i] = *(const f32x4*)(xrow + (size_t)(c0 + i) * N);
#pragma unroll
        for (int k = 0; k < 4; ++k) {
            const int n = 4 * nq + k;
            bf16x4 hb;
#pragma unroll
            for (int i = 0; i < 4; ++i) {
                part[k] += q[i][k] * q[i][k];
                hb[i] = (__bf16)q[i][k];
            }
            *(u16x4*)(&tsT[n * 256 + (c0 ^ swz(n))]) = __builtin_bit_cast(u16x4, hb);
        }
    }
#pragma unroll
    for (int k = 0; k < 4; ++k) xred[cq][4 * nq + k] = part[k];
    __syncthreads();
    if (t < 64) {
        float s = 0.f;
#pragma unroll
        for (int j = 0; j < 16; ++j) s += xred[j][t];
        xsq[(size_t)b * N + nb * 64 + t] = s;
    }
    // ---- phase B1: xbt coalesced write ----
    {
        const int l = t & 31, nh = t >> 5;
#pragma unroll
        for (int j = 0; j < 8; ++j) {
            const int n = nh + 8 * j;
            const int c0 = l * 8;
            const u16x8 v = *(const u16x8*)(&tsT[n * 256 + (c0 ^ swz(n))]);
            *(u16x8*)(xbt + ((size_t)b * N + nb * 64 + n) * C + c0) = v;
        }
    }
    // ---- phase B2: logits MFMA (W f32 -> bf16 in-reg) ----
    const int wv = t >> 6, lane = t & 63, li = lane & 15, lk = lane >> 4;
    const f32x4 zv = {0.f, 0.f, 0.f, 0.f};
    f32x4 acc[4] = {zv, zv, zv, zv};
    const float* wr = Wf + (size_t)(wv * 16 + li) * C + lk * 8;
#pragma unroll
    for (int c0 = 0; c0 < C; c0 += 32) {
        const s16x8 bfrag = cvt8(*(const f32x4*)(wr + c0), *(const f32x4*)(wr + c0 + 4));
#pragma unroll
        for (int s = 0; s < 4; ++s) {
            const int n = s * 16 + li;
            const s16x8 a = *(const s16x8*)(&tsT[n * 256 + ((lk * 8 + c0) ^ swz(n))]);
            acc[s] = MFMA(a, bfrag, acc[s]);
        }
    }
    unsigned short* Srow = Sb + ((size_t)b * M + wv * 16 + li) * N + nb * 64;
#pragma unroll
    for (int s = 0; s < 4; ++s) {
        bf16x4 h;
#pragma unroll
        for (int r = 0; r < 4; ++r) h[r] = (__bf16)acc[s][r];
        *(u16x4*)(Srow + s * 16 + lk * 4) = __builtin_bit_cast(u16x4, h);
    }
}

// ---------------------------------------------------------------------------
// K2: softmax over n per (b,m); bf16 in -> bf16 out.
// ---------------------------------------------------------------------------
__global__ __launch_bounds__(256) void k2_softmax_n(const unsigned short* __restrict__ Sb,
                                                    unsigned short* __restrict__ Pb) {
    const int m = blockIdx.x, b = blockIdx.y;
    const unsigned short* col = Sb + ((size_t)b * M + m) * N;
    unsigned short* po = Pb + ((size_t)b * M + m) * N;
    const int t = threadIdx.x;
    float v[16];
    const u16x8 h0 = *(const u16x8*)(col + t * 16);
    const u16x8 h1 = *(const u16x8*)(col + t * 16 + 8);
#pragma unroll
    for (int i = 0; i < 8; ++i) v[i] = bf2f(h0[i]);
#pragma unroll
    for (int i = 0; i < 8; ++i) v[8 + i] = bf2f(h1[i]);
    float mx = -INFINITY;
#pragma unroll
    for (int i = 0; i < 16; ++i) mx = fmaxf(mx, v[i]);
#pragma unroll
    for (int off = 32; off >= 1; off >>= 1) mx = fmaxf(mx, __shfl_xor(mx, off));
    __shared__ float redm[4], reds[4];
    const int wave = t >> 6, lane = t & 63;
    if (lane == 0) redm[wave] = mx;
    __syncthreads();
    mx = fmaxf(fmaxf(redm[0], redm[1]), fmaxf(redm[2], redm[3]));
    float s = 0.f;
#pragma unroll
    for (int i = 0; i < 16; ++i) {
        v[i] = __expf(v[i] - mx);
        s += v[i];
    }
#pragma unroll
    for (int off = 32; off >= 1; off >>= 1) s += __shfl_xor(s, off);
    if (lane == 0) reds[wave] = s;
    __syncthreads();
    s = reds[0] + reds[1] + reds[2] + reds[3];
    const float inv = 1.f / s;
    bf16x8 o0, o1;
#pragma unroll
    for (int i = 0; i < 8; ++i) o0[i] = (__bf16)(v[i] * inv);
#pragma unroll
    for (int i = 0; i < 8; ++i) o1[i] = (__bf16)(v[8 + i] * inv);
    *(u16x8*)(po + t * 16) = __builtin_bit_cast(u16x8, o0);
    *(u16x8*)(po + t * 16 + 8) = __builtin_bit_cast(u16x8, o1);
}

// ---------------------------------------------------------------------------
// K3: proto partials parts[b][ck][m][c] over 512-n chunks.
// m-SPLIT: grid (8, 2, B) -> 512 blocks (2/CU), each block 32 m-rows.
// x tile re-read by both halves is L3-resident. parts bitwise identical.
// ---------------------------------------------------------------------------
__global__ __launch_bounds__(256) void k3_mfma(const float* __restrict__ x,
                                               const unsigned short* __restrict__ Pb,
                                               float* __restrict__ parts) {
    const int ck = blockIdx.x, mh = blockIdx.y, b = blockIdx.z;
    const int wv = threadIdx.x >> 6, lane = threadIdx.x & 63;
    const int li = lane & 15, lk = lane >> 4;
    const int c0w = wv * 64;
    const int nb = ck * 512;
    const f32x4 zv = {0.f, 0.f, 0.f, 0.f};
    f32x4 acc[4][2];
#pragma unroll
    for (int s = 0; s < 4; ++s)
#pragma unroll
        for (int u = 0; u < 2; ++u) acc[s][u] = zv;
    const float* ar = x + ((size_t)b * C + c0w + li) * N + nb + lk * 8;
    const unsigned short* br = Pb + ((size_t)b * M + mh * 32 + li) * N + nb + lk * 8;
#pragma unroll 4
    for (int n0 = 0; n0 < 512; n0 += 32) {
        s16x8 af[4], bf_[2];
#pragma unroll
        for (int s = 0; s < 4; ++s) {
            const float* p = ar + (size_t)(s * 16) * N + n0;
            af[s] = cvt8(*(const f32x4*)p, *(const f32x4*)(p + 4));
        }
#pragma unroll
        for (int u = 0; u < 2; ++u) bf_[u] = *(const s16x8*)(br + (size_t)(u * 16) * N + n0);
#pragma unroll
        for (int s = 0; s < 4; ++s)
#pragma unroll
            for (int u = 0; u < 2; ++u) acc[s][u] = MFMA(af[s], bf_[u], acc[s][u]);
    }
    float* pp = parts + ((size_t)b * 8 + ck) * M * C;
#pragma unroll
    for (int s = 0; s < 4; ++s)
#pragma unroll
        for (int u = 0; u < 2; ++u)
            *(f32x4*)(pp + (size_t)(mh * 32 + u * 16 + li) * C + c0w + s * 16 + lk * 4) =
                acc[s][u];
}

// ---------------------------------------------------------------------------
// K3b: reduce 8 chunks -> l2norm -> proto_bf [m][c], protoT_bf [c][m], p2.
// ---------------------------------------------------------------------------
__global__ __launch_bounds__(256) void k3b_reduce(const float* __restrict__ parts,
                                                  unsigned short* __restrict__ proto_bf,
                                                  unsigned short* __restrict__ protoT_bf,
                                                  float* __restrict__ p2) {
    const int mb = blockIdx.x, b = blockIdx.y;
    const int t = threadIdx.x;
    const int ml = t >> 5, cl = t & 31;
    const int m = mb * 8 + ml;
    const int c0 = cl * 8;
    float v[8] = {0.f, 0.f, 0.f, 0.f, 0.f, 0.f, 0.f, 0.f};
    const float* pbase = parts + (size_t)b * 8 * M * C + (size_t)m * C + c0;
#pragma unroll
    for (int ck = 0; ck < 8; ++ck) {
        const f32x4 q0 = *(const f32x4*)(pbase + (size_t)ck * M * C);
        const f32x4 q1 = *(const f32x4*)(pbase + (size_t)ck * M * C + 4);
#pragma unroll
        for (int j = 0; j < 4; ++j) { v[j] += q0[j]; v[4 + j] += q1[j]; }
    }
    float sq = 0.f;
#pragma unroll
    for (int j = 0; j < 8; ++j) sq += v[j] * v[j];
#pragma unroll
    for (int off = 16; off >= 1; off >>= 1) sq += __shfl_xor(sq, off);
    const float denom = fmaxf(sqrtf(sq), EPS);
    const float scale = 1.f / denom;
    if (cl == 0) p2[b * M + m] = sq / (denom * denom);
    bf16x8 h;
#pragma unroll
    for (int j = 0; j < 8; ++j) h[j] = (__bf16)(v[j] * scale);
    const u16x8 hu = __builtin_bit_cast(u16x8, h);
    *(u16x8*)(proto_bf + ((size_t)b * M + m) * C + c0) = hu;
#pragma unroll
    for (int j = 0; j < 8; ++j)
        protoT_bf[((size_t)b * C + c0 + j) * M + m] = hu[j];
}

// ---------------------------------------------------------------------------
// K4: score + softmax-m (unnormalized; 1/sum cancels in L2-norm) + compact
// partials -> pnm bf16 [b][n][m].
// ---------------------------------------------------------------------------
__global__ __launch_bounds__(256) void k4_score(const unsigned short* __restrict__ proto_bf,
                                                const unsigned short* __restrict__ xbt,
                                                const float* __restrict__ p2,
                                                const float* __restrict__ xsq,
                                                unsigned short* __restrict__ pnm,
                                                float* __restrict__ cparts) {
    const int b = blockIdx.y;
    const int wv = threadIdx.x >> 6, lane = threadIdx.x & 63;
    const int li = lane & 15, lk = lane >> 4;
    const int nbase = blockIdx.x * 256 + wv * 64;
    const f32x4 zv = {0.f, 0.f, 0.f, 0.f};
    f32x4 acc[4][4];
#pragma unroll
    for (int s = 0; s < 4; ++s)
#pragma unroll
        for (int u = 0; u < 4; ++u) acc[s][u] = zv;
    const unsigned short* ar = proto_bf + ((size_t)b * M + li) * C + lk * 8;
    const unsigned short* br = xbt + ((size_t)b * N + nbase + li) * C + lk * 8;
#pragma unroll
    for (int c0 = 0; c0 < C; c0 += 32) {
        s16x8 af[4], bf_[4];
#pragma unroll
        for (int s = 0; s < 4; ++s) af[s] = *(const s16x8*)(ar + (size_t)(s * 16) * C + c0);
#pragma unroll
        for (int u = 0; u < 4; ++u) bf_[u] = *(const s16x8*)(br + (size_t)(u * 16) * C + c0);
#pragma unroll
        for (int s = 0; s < 4; ++s)
#pragma unroll
            for (int u = 0; u < 4; ++u) acc[s][u] = MFMA(af[s], bf_[u], acc[s][u]);
    }
    float csum = 0.f;
#pragma unroll
    for (int u = 0; u < 4; ++u) {
        const int n = nbase + u * 16 + li;
        float vmax = -INFINITY;
#pragma unroll
        for (int s = 0; s < 4; ++s)
#pragma unroll
            for (int r = 0; r < 4; ++r) vmax = fmaxf(vmax, acc[s][u][r]);
        vmax = fmaxf(vmax, __shfl_xor(vmax, 16));
        vmax = fmaxf(vmax, __shfl_xor(vmax, 32));
        int t1 = 1 << 30;
#pragma unroll
        for (int s = 0; s < 4; ++s)
#pragma unroll
            for (int r = 0; r < 4; ++r)
                if (acc[s][u][r] == vmax) t1 = min(t1, s * 16 + lk * 4 + r);
        t1 = min(t1, __shfl_xor(t1, 16));
        t1 = min(t1, __shfl_xor(t1, 32));
        unsigned short* prow = pnm + ((size_t)b * N + n) * M;
#pragma unroll
        for (int s = 0; s < 4; ++s) {
            bf16x4 h;
#pragma unroll
            for (int r = 0; r < 4; ++r) h[r] = (__bf16)__expf(acc[s][u][r] - vmax);
            *(u16x4*)(prow + s * 16 + lk * 4) = __builtin_bit_cast(u16x4, h);
        }
        if (lk == 0) csum += xsq[(size_t)b * N + n] - 2.f * vmax + p2[b * M + t1];
    }
#pragma unroll
    for (int off = 32; off >= 1; off >>= 1) csum += __shfl_xor(csum, off);
    __shared__ float red[4];
    if (lane == 0) red[wv] = csum;
    __syncthreads();
    if (threadIdx.x == 0)
        cparts[b * 16 + blockIdx.x] = red[0] + red[1] + red[2] + red[3];
}

// ---------------------------------------------------------------------------
// K4b: out = l2norm_c(sum_m p[n][m]*protoT[c][m]).
// ---------------------------------------------------------------------------
__global__ __launch_bounds__(256) void k4b_mfma(const unsigned short* __restrict__ pnm,
                                                const unsigned short* __restrict__ protoT_bf,
                                                float* __restrict__ out) {
    const int b = blockIdx.y;
    const int wv = threadIdx.x >> 6, lane = threadIdx.x & 63;
    const int li = lane & 15, lk = lane >> 4;
    const int n0 = blockIdx.x * 64;
    const int cb = wv * 64;
    const f32x4 zv = {0.f, 0.f, 0.f, 0.f};
    f32x4 acc[4][4];
#pragma unroll
    for (int s = 0; s < 4; ++s)
#pragma unroll
        for (int u = 0; u < 4; ++u) acc[s][u] = zv;
    const unsigned short* ar = pnm + ((size_t)b * N + n0 + li) * M + lk * 8;
    const unsigned short* br = protoT_bf + ((size_t)b * C + cb + li) * M + lk * 8;
#pragma unroll
    for (int m0 = 0; m0 < M; m0 += 32) {
        s16x8 af[4], bf_[4];
#pragma unroll
        for (int s = 0; s < 4; ++s) af[s] = *(const s16x8*)(ar + (size_t)(s * 16) * M + m0);
#pragma unroll
        for (int u = 0; u < 4; ++u) bf_[u] = *(const s16x8*)(br + (size_t)(u * 16) * M + m0);
#pragma unroll
        for (int s = 0; s < 4; ++s)
#pragma unroll
            for (int u = 0; u < 4; ++u) acc[s][u] = MFMA(af[s], bf_[u], acc[s][u]);
    }
    __shared__ float ls[4][64];
    __shared__ float ls2[64];
    float psq[4][4];
#pragma unroll
    for (int s = 0; s < 4; ++s)
#pragma unroll
        for (int r = 0; r < 4; ++r) {
            float sum = 0.f;
#pragma unroll
            for (int u = 0; u < 4; ++u) sum += acc[s][u][r] * acc[s][u][r];
#pragma unroll
            for (int off = 8; off >= 1; off >>= 1) sum += __shfl_xor(sum, off);
            psq[s][r] = sum;
        }
    if (li == 0) {
#pragma unroll
        for (int s = 0; s < 4; ++s)
#pragma unroll
            for (int r = 0; r < 4; ++r) ls[wv][s * 16 + lk * 4 + r] = psq[s][r];
    }
    __syncthreads();
    if (threadIdx.x < 64) {
        const int tt = threadIdx.x;
        const float tot = ls[0][tt] + ls[1][tt] + ls[2][tt] + ls[3][tt];
        ls2[tt] = 1.f / fmaxf(sqrtf(tot), EPS);
    }
    __syncthreads();
    float scl[4][4];
#pragma unroll
    for (int s = 0; s < 4; ++s)
#pragma unroll
        for (int r = 0; r < 4; ++r) scl[s][r] = ls2[s * 16 + lk * 4 + r];
    float* ob = out + (size_t)b * C * N;
#pragma unroll
    for (int s = 0; s < 4; ++s)
#pragma unroll
        for (int u = 0; u < 4; ++u) {
            f32x4 q;
#pragma unroll
            for (int r = 0; r < 4; ++r) q[r] = acc[s][u][r] * scl[s][r];
            *(f32x4*)(ob + (size_t)(cb + u * 16 + li) * N + n0 + s * 16 + lk * 4) = q;
        }
}

// ---------------------------------------------------------------------------
// K5 / K6: losses.
// ---------------------------------------------------------------------------
__global__ __launch_bounds__(256) void k5_dis(const unsigned short* __restrict__ proto_bf,
                                              const float* __restrict__ p2,
                                              float* __restrict__ dparts) {
    const int q = blockIdx.x;
    const int b = blockIdx.y;
    const unsigned short* pr = proto_bf + (size_t)b * M * C;
    __shared__ float pl[M * C];
    for (int idx = threadIdx.x; idx < M * C; idx += 256) {
        int m = idx >> 8, c = idx & 255;
        pl[m * 256 + (c ^ (m & 31))] = bf2f(pr[idx]);
    }
    __syncthreads();
    float sum = 0.f;
    for (int k = 0; k < 2; ++k) {
        const int pair = q * 512 + k * 256 + threadIdx.x;
        const int i = pair >> 6, j = pair & 63;
        if (j > i) {
            float g = 0.f;
#pragma unroll 8
            for (int c = 0; c < C; ++c)
                g += pl[i * 256 + (c ^ (i & 31))] * pl[j * 256 + (c ^ (j & 31))];
            const float d = 1.f - (p2[b * M + i] + p2[b * M + j] - 2.f * g);
            sum += fmaxf(d, 0.f);
        }
    }
#pragma unroll
    for (int off = 32; off >= 1; off >>= 1) sum += __shfl_xor(sum, off);
    __shared__ float red[4];
    const int wave = threadIdx.x >> 6, lane = threadIdx.x & 63;
    if (lane == 0) red[wave] = sum;
    __syncthreads();
    if (threadIdx.x == 0) dparts[b * 8 + q] = red[0] + red[1] + red[2] + red[3];
}

__global__ __launch_bounds__(256) void k6_final(const float* __restrict__ cparts, int ncp,
                                                const float* __restrict__ dparts,
                                                float* __restrict__ losses) {
    const int t = threadIdx.x;
    float cs = 0.f;
    for (int i = t; i < ncp; i += 256) cs += cparts[i];
    float ds = dparts[t];
#pragma unroll
    for (int off = 32; off >= 1; off >>= 1) {
        cs += __shfl_xor(cs, off);
        ds += __shfl_xor(ds, off);
    }
    __shared__ float rc[4], rd[4];
    const int wave = t >> 6, lane = t & 63;
    if (lane == 0) { rc[wave] = cs; rd[wave] = ds; }
    __syncthreads();
    if (t == 0) {
        const float ctot = rc[0] + rc[1] + rc[2] + rc[3];
        const float dtot = rd[0] + rd[1] + rd[2] + rd[3];
        losses[0] = ctot / ((float)B * (float)N * (float)C);
        losses[1] = dtot * (2.f / (float)(M * (M - 1))) / (float)B;
    }
}

extern "C" void kernel_launch(void* const* d_in, const int* in_sizes, int n_in,
                              void* d_out, int out_size, void* d_ws, size_t ws_size,
                              hipStream_t stream) {
    const float* x = (const float*)d_in[0];
    const float* Wf = (const float*)d_in[1];
    float* out = (float*)d_out;
    float* wsf = (float*)d_ws;
    float* losses = out + (size_t)B * C * N;

    // Proven layout (r3/r4/r7): xbt in d_out (dead before k4b overwrites), rest in ws.
    unsigned short* xbt = (unsigned short*)d_out;
    unsigned short* Sbf = (unsigned short*)wsf;
    float* parts = wsf;
    unsigned short* Pbf = (unsigned short*)(wsf + 4194304);
    unsigned short* pnm = Pbf;
    float* xsq = wsf + 8388608;
    unsigned short* proto_bf = (unsigned short*)(wsf + 8519680);
    unsigned short* protoT_bf = (unsigned short*)(wsf + 8781824);
    float* p2 = wsf + 9052160;
    float* cparts = wsf + 9054208;
    float* dparts = wsf + 9054720;

    k01<<<dim3(N / 64, B), 256, 0, stream>>>(x, Wf, xbt, Sbf, xsq);
    k2_softmax_n<<<dim3(M, B), 256, 0, stream>>>(Sbf, Pbf);
    k3_mfma<<<dim3(8, 2, B), 256, 0, stream>>>(x, Pbf, parts);
    k3b_reduce<<<dim3(8, B), 256, 0, stream>>>(parts, proto_bf, protoT_bf, p2);
    k4_score<<<dim3(N / 256, B), 256, 0, stream>>>(proto_bf, xbt, p2, xsq, pnm, cparts);
    k4b_mfma<<<dim3(N / 64, B), 256, 0, stream>>>(pnm, protoT_bf, out);
    k5_dis<<<dim3(8, B), 256, 0, stream>>>(proto_bf, p2, dparts);
    k6_final<<<1, 256, 0, stream>>>(cparts, B * 16, dparts, losses);
}

// Round 11
// 178.117 us; speedup vs baseline: 1.1553x; 1.0165x over previous
//
#include <hip/hip_runtime.h>
#include <math.h>

#define B 32
#define C 256
#define M 64
#define N 4096  // H*W

typedef __attribute__((ext_vector_type(8))) short s16x8;
typedef __attribute__((ext_vector_type(8))) __bf16 bf16x8;
typedef __attribute__((ext_vector_type(4))) __bf16 bf16x4;
typedef __attribute__((ext_vector_type(4))) float f32x4;
typedef __attribute__((ext_vector_type(4))) unsigned short u16x4;
typedef __attribute__((ext_vector_type(8))) unsigned short u16x8;

static constexpr float EPS = 1e-12f;

__device__ __forceinline__ float bf2f(unsigned short h) {
    return __uint_as_float((unsigned)h << 16);
}
__device__ __forceinline__ f32x4 MFMA(s16x8 a, s16x8 b, f32x4 c) {
    return __builtin_amdgcn_mfma_f32_16x16x32_bf16(
        __builtin_bit_cast(bf16x8, a), __builtin_bit_cast(bf16x8, b), c, 0, 0, 0);
}
__device__ __forceinline__ s16x8 cvt8(const f32x4 a, const f32x4 b) {
    bf16x8 h;
    h[0] = (__bf16)a[0]; h[1] = (__bf16)a[1]; h[2] = (__bf16)a[2]; h[3] = (__bf16)a[3];
    h[4] = (__bf16)b[0]; h[5] = (__bf16)b[1]; h[6] = (__bf16)b[2]; h[7] = (__bf16)b[3];
    return __builtin_bit_cast(s16x8, h);
}
// LDS column swizzle for the [n][c] bf16 tile (halfword units, flips bits 3-5 of c)
__device__ __forceinline__ int swz(int n) {
    return (((n >> 2) & 3) | ((n & 1) << 2)) << 3;
}

// ---------------------------------------------------------------------------
// K01: fused convert + transpose + logits (r7-proven version, 74.8us).
// ---------------------------------------------------------------------------
__global__ __launch_bounds__(256) void k01(const float* __restrict__ x,
                                           const float* __restrict__ Wf,
                                           unsigned short* __restrict__ xbt,
                                           unsigned short* __restrict__ Sb,
                                           float* __restrict__ xsq) {
    const int nb = blockIdx.x, b = blockIdx.y;
    const int t = threadIdx.x;
    __shared__ unsigned short tsT[64 * 256];
    __shared__ float xred[16][68];
    // ---- phase A: load 4c x 4n register blocks, cvt, stage to LDS ----
    const int nq = t & 15, cq = t >> 4;
    float part[4] = {0.f, 0.f, 0.f, 0.f};
    const float* xrow = x + (size_t)b * C * N + (size_t)nb * 64 + 4 * nq;
#pragma unroll
    for (int step = 0; step < 4; ++step) {
        const int c0 = cq * 4 + step * 64;
        f32x4 q[4];
#pragma unroll
        for (int i = 0; i < 4; ++i) q[i] = *(const f32x4*)(xrow + (size_t)(c0 + i) * N);
#pragma unroll
        for (int k = 0; k < 4; ++k) {
            const int n = 4 * nq + k;
            bf16x4 hb;
#pragma unroll
            for (int i = 0; i < 4; ++i) {
                part[k] += q[i][k] * q[i][k];
                hb[i] = (__bf16)q[i][k];
            }
            *(u16x4*)(&tsT[n * 256 + (c0 ^ swz(n))]) = __builtin_bit_cast(u16x4, hb);
        }
    }
#pragma unroll
    for (int k = 0; k < 4; ++k) xred[cq][4 * nq + k] = part[k];
    __syncthreads();
    if (t < 64) {
        float s = 0.f;
#pragma unroll
        for (int j = 0; j < 16; ++j) s += xred[j][t];
        xsq[(size_t)b * N + nb * 64 + t] = s;
    }
    // ---- phase B1: xbt coalesced write ----
    {
        const int l = t & 31, nh = t >> 5;
#pragma unroll
        for (int j = 0; j < 8; ++j) {
            const int n = nh + 8 * j;
            const int c0 = l * 8;
            const u16x8 v = *(const u16x8*)(&tsT[n * 256 + (c0 ^ swz(n))]);
            *(u16x8*)(xbt + ((size_t)b * N + nb * 64 + n) * C + c0) = v;
        }
    }
    // ---- phase B2: logits MFMA (W f32 -> bf16 in-reg) ----
    const int wv = t >> 6, lane = t & 63, li = lane & 15, lk = lane >> 4;
    const f32x4 zv = {0.f, 0.f, 0.f, 0.f};
    f32x4 acc[4] = {zv, zv, zv, zv};
    const float* wr = Wf + (size_t)(wv * 16 + li) * C + lk * 8;
#pragma unroll
    for (int c0 = 0; c0 < C; c0 += 32) {
        const s16x8 bfrag = cvt8(*(const f32x4*)(wr + c0), *(const f32x4*)(wr + c0 + 4));
#pragma unroll
        for (int s = 0; s < 4; ++s) {
            const int n = s * 16 + li;
            const s16x8 a = *(const s16x8*)(&tsT[n * 256 + ((lk * 8 + c0) ^ swz(n))]);
            acc[s] = MFMA(a, bfrag, acc[s]);
        }
    }
    unsigned short* Srow = Sb + ((size_t)b * M + wv * 16 + li) * N + nb * 64;
#pragma unroll
    for (int s = 0; s < 4; ++s) {
        bf16x4 h;
#pragma unroll
        for (int r = 0; r < 4; ++r) h[r] = (__bf16)acc[s][r];
        *(u16x4*)(Srow + s * 16 + lk * 4) = __builtin_bit_cast(u16x4, h);
    }
}

// ---------------------------------------------------------------------------
// K2: softmax over n per (b,m); bf16 in -> bf16 out.
// ---------------------------------------------------------------------------
__global__ __launch_bounds__(256) void k2_softmax_n(const unsigned short* __restrict__ Sb,
                                                    unsigned short* __restrict__ Pb) {
    const int m = blockIdx.x, b = blockIdx.y;
    const unsigned short* col = Sb + ((size_t)b * M + m) * N;
    unsigned short* po = Pb + ((size_t)b * M + m) * N;
    const int t = threadIdx.x;
    float v[16];
    const u16x8 h0 = *(const u16x8*)(col + t * 16);
    const u16x8 h1 = *(const u16x8*)(col + t * 16 + 8);
#pragma unroll
    for (int i = 0; i < 8; ++i) v[i] = bf2f(h0[i]);
#pragma unroll
    for (int i = 0; i < 8; ++i) v[8 + i] = bf2f(h1[i]);
    float mx = -INFINITY;
#pragma unroll
    for (int i = 0; i < 16; ++i) mx = fmaxf(mx, v[i]);
#pragma unroll
    for (int off = 32; off >= 1; off >>= 1) mx = fmaxf(mx, __shfl_xor(mx, off));
    __shared__ float redm[4], reds[4];
    const int wave = t >> 6, lane = t & 63;
    if (lane == 0) redm[wave] = mx;
    __syncthreads();
    mx = fmaxf(fmaxf(redm[0], redm[1]), fmaxf(redm[2], redm[3]));
    float s = 0.f;
#pragma unroll
    for (int i = 0; i < 16; ++i) {
        v[i] = __expf(v[i] - mx);
        s += v[i];
    }
#pragma unroll
    for (int off = 32; off >= 1; off >>= 1) s += __shfl_xor(s, off);
    if (lane == 0) reds[wave] = s;
    __syncthreads();
    s = reds[0] + reds[1] + reds[2] + reds[3];
    const float inv = 1.f / s;
    bf16x8 o0, o1;
#pragma unroll
    for (int i = 0; i < 8; ++i) o0[i] = (__bf16)(v[i] * inv);
#pragma unroll
    for (int i = 0; i < 8; ++i) o1[i] = (__bf16)(v[8 + i] * inv);
    *(u16x8*)(po + t * 16) = __builtin_bit_cast(u16x8, o0);
    *(u16x8*)(po + t * 16 + 8) = __builtin_bit_cast(u16x8, o1);
}

// ---------------------------------------------------------------------------
// K3: proto partials parts[b][ck][m][c] over 512-n chunks.
// c-SPLIT: grid (8, 2, B) -> 512 blocks (2/CU). Each block: 128 c x 64 m.
// x partitions disjointly across blocks (no duplicate HBM reads, unlike the
// failed m-split); only small Pb read duplicates (L2-resident).
// Accumulation order per output element identical -> parts bitwise identical.
// ---------------------------------------------------------------------------
__global__ __launch_bounds__(256) void k3_mfma(const float* __restrict__ x,
                                               const unsigned short* __restrict__ Pb,
                                               float* __restrict__ parts) {
    const int ck = blockIdx.x, ch = blockIdx.y, b = blockIdx.z;
    const int wv = threadIdx.x >> 6, lane = threadIdx.x & 63;
    const int li = lane & 15, lk = lane >> 4;
    const int c0w = ch * 128 + wv * 32;  // this wave's 32 c-rows
    const int nb = ck * 512;
    const f32x4 zv = {0.f, 0.f, 0.f, 0.f};
    f32x4 acc[2][4];
#pragma unroll
    for (int s = 0; s < 2; ++s)
#pragma unroll
        for (int u = 0; u < 4; ++u) acc[s][u] = zv;
    const float* ar = x + ((size_t)b * C + c0w + li) * N + nb + lk * 8;
    const unsigned short* br = Pb + ((size_t)b * M + li) * N + nb + lk * 8;
#pragma unroll 4
    for (int n0 = 0; n0 < 512; n0 += 32) {
        s16x8 af[2], bf_[4];
#pragma unroll
        for (int s = 0; s < 2; ++s) {
            const float* p = ar + (size_t)(s * 16) * N + n0;
            af[s] = cvt8(*(const f32x4*)p, *(const f32x4*)(p + 4));
        }
#pragma unroll
        for (int u = 0; u < 4; ++u) bf_[u] = *(const s16x8*)(br + (size_t)(u * 16) * N + n0);
#pragma unroll
        for (int s = 0; s < 2; ++s)
#pragma unroll
            for (int u = 0; u < 4; ++u) acc[s][u] = MFMA(af[s], bf_[u], acc[s][u]);
    }
    float* pp = parts + ((size_t)b * 8 + ck) * M * C;
#pragma unroll
    for (int s = 0; s < 2; ++s)
#pragma unroll
        for (int u = 0; u < 4; ++u)
            *(f32x4*)(pp + (size_t)(u * 16 + li) * C + c0w + s * 16 + lk * 4) = acc[s][u];
}

// ---------------------------------------------------------------------------
// K3b: reduce 8 chunks -> l2norm -> proto_bf [m][c], protoT_bf [c][m], p2.
// ---------------------------------------------------------------------------
__global__ __launch_bounds__(256) void k3b_reduce(const float* __restrict__ parts,
                                                  unsigned short* __restrict__ proto_bf,
                                                  unsigned short* __restrict__ protoT_bf,
                                                  float* __restrict__ p2) {
    const int mb = blockIdx.x, b = blockIdx.y;
    const int t = threadIdx.x;
    const int ml = t >> 5, cl = t & 31;
    const int m = mb * 8 + ml;
    const int c0 = cl * 8;
    float v[8] = {0.f, 0.f, 0.f, 0.f, 0.f, 0.f, 0.f, 0.f};
    const float* pbase = parts + (size_t)b * 8 * M * C + (size_t)m * C + c0;
#pragma unroll
    for (int ck = 0; ck < 8; ++ck) {
        const f32x4 q0 = *(const f32x4*)(pbase + (size_t)ck * M * C);
        const f32x4 q1 = *(const f32x4*)(pbase + (size_t)ck * M * C + 4);
#pragma unroll
        for (int j = 0; j < 4; ++j) { v[j] += q0[j]; v[4 + j] += q1[j]; }
    }
    float sq = 0.f;
#pragma unroll
    for (int j = 0; j < 8; ++j) sq += v[j] * v[j];
#pragma unroll
    for (int off = 16; off >= 1; off >>= 1) sq += __shfl_xor(sq, off);
    const float denom = fmaxf(sqrtf(sq), EPS);
    const float scale = 1.f / denom;
    if (cl == 0) p2[b * M + m] = sq / (denom * denom);
    bf16x8 h;
#pragma unroll
    for (int j = 0; j < 8; ++j) h[j] = (__bf16)(v[j] * scale);
    const u16x8 hu = __builtin_bit_cast(u16x8, h);
    *(u16x8*)(proto_bf + ((size_t)b * M + m) * C + c0) = hu;
#pragma unroll
    for (int j = 0; j < 8; ++j)
        protoT_bf[((size_t)b * C + c0 + j) * M + m] = hu[j];
}

// ---------------------------------------------------------------------------
// K4: score + softmax-m (unnormalized; 1/sum cancels in L2-norm) + compact
// partials -> pnm bf16 [b][n][m].
// ---------------------------------------------------------------------------
__global__ __launch_bounds__(256) void k4_score(const unsigned short* __restrict__ proto_bf,
                                                const unsigned short* __restrict__ xbt,
                                                const float* __restrict__ p2,
                                                const float* __restrict__ xsq,
                                                unsigned short* __restrict__ pnm,
                                                float* __restrict__ cparts) {
    const int b = blockIdx.y;
    const int wv = threadIdx.x >> 6, lane = threadIdx.x & 63;
    const int li = lane & 15, lk = lane >> 4;
    const int nbase = blockIdx.x * 256 + wv * 64;
    const f32x4 zv = {0.f, 0.f, 0.f, 0.f};
    f32x4 acc[4][4];
#pragma unroll
    for (int s = 0; s < 4; ++s)
#pragma unroll
        for (int u = 0; u < 4; ++u) acc[s][u] = zv;
    const unsigned short* ar = proto_bf + ((size_t)b * M + li) * C + lk * 8;
    const unsigned short* br = xbt + ((size_t)b * N + nbase + li) * C + lk * 8;
#pragma unroll
    for (int c0 = 0; c0 < C; c0 += 32) {
        s16x8 af[4], bf_[4];
#pragma unroll
        for (int s = 0; s < 4; ++s) af[s] = *(const s16x8*)(ar + (size_t)(s * 16) * C + c0);
#pragma unroll
        for (int u = 0; u < 4; ++u) bf_[u] = *(const s16x8*)(br + (size_t)(u * 16) * C + c0);
#pragma unroll
        for (int s = 0; s < 4; ++s)
#pragma unroll
            for (int u = 0; u < 4; ++u) acc[s][u] = MFMA(af[s], bf_[u], acc[s][u]);
    }
    float csum = 0.f;
#pragma unroll
    for (int u = 0; u < 4; ++u) {
        const int n = nbase + u * 16 + li;
        float vmax = -INFINITY;
#pragma unroll
        for (int s = 0; s < 4; ++s)
#pragma unroll
            for (int r = 0; r < 4; ++r) vmax = fmaxf(vmax, acc[s][u][r]);
        vmax = fmaxf(vmax, __shfl_xor(vmax, 16));
        vmax = fmaxf(vmax, __shfl_xor(vmax, 32));
        int t1 = 1 << 30;
#pragma unroll
        for (int s = 0; s < 4; ++s)
#pragma unroll
            for (int r = 0; r < 4; ++r)
                if (acc[s][u][r] == vmax) t1 = min(t1, s * 16 + lk * 4 + r);
        t1 = min(t1, __shfl_xor(t1, 16));
        t1 = min(t1, __shfl_xor(t1, 32));
        unsigned short* prow = pnm + ((size_t)b * N + n) * M;
#pragma unroll
        for (int s = 0; s < 4; ++s) {
            bf16x4 h;
#pragma unroll
            for (int r = 0; r < 4; ++r) h[r] = (__bf16)__expf(acc[s][u][r] - vmax);
            *(u16x4*)(prow + s * 16 + lk * 4) = __builtin_bit_cast(u16x4, h);
        }
        if (lk == 0) csum += xsq[(size_t)b * N + n] - 2.f * vmax + p2[b * M + t1];
    }
#pragma unroll
    for (int off = 32; off >= 1; off >>= 1) csum += __shfl_xor(csum, off);
    __shared__ float red[4];
    if (lane == 0) red[wv] = csum;
    __syncthreads();
    if (threadIdx.x == 0)
        cparts[b * 16 + blockIdx.x] = red[0] + red[1] + red[2] + red[3];
}

// ---------------------------------------------------------------------------
// K4b: out = l2norm_c(sum_m p[n][m]*protoT[c][m]).
// ---------------------------------------------------------------------------
__global__ __launch_bounds__(256) void k4b_mfma(const unsigned short* __restrict__ pnm,
                                                const unsigned short* __restrict__ protoT_bf,
                                                float* __restrict__ out) {
    const int b = blockIdx.y;
    const int wv = threadIdx.x >> 6, lane = threadIdx.x & 63;
    const int li = lane & 15, lk = lane >> 4;
    const int n0 = blockIdx.x * 64;
    const int cb = wv * 64;
    const f32x4 zv = {0.f, 0.f, 0.f, 0.f};
    f32x4 acc[4][4];
#pragma unroll
    for (int s = 0; s < 4; ++s)
#pragma unroll
        for (int u = 0; u < 4; ++u) acc[s][u] = zv;
    const unsigned short* ar = pnm + ((size_t)b * N + n0 + li) * M + lk * 8;
    const unsigned short* br = protoT_bf + ((size_t)b * C + cb + li) * M + lk * 8;
#pragma unroll
    for (int m0 = 0; m0 < M; m0 += 32) {
        s16x8 af[4], bf_[4];
#pragma unroll
        for (int s = 0; s < 4; ++s) af[s] = *(const s16x8*)(ar + (size_t)(s * 16) * M + m0);
#pragma unroll
        for (int u = 0; u < 4; ++u) bf_[u] = *(const s16x8*)(br + (size_t)(u * 16) * M + m0);
#pragma unroll
        for (int s = 0; s < 4; ++s)
#pragma unroll
            for (int u = 0; u < 4; ++u) acc[s][u] = MFMA(af[s], bf_[u], acc[s][u]);
    }
    __shared__ float ls[4][64];
    __shared__ float ls2[64];
    float psq[4][4];
#pragma unroll
    for (int s = 0; s < 4; ++s)
#pragma unroll
        for (int r = 0; r < 4; ++r) {
            float sum = 0.f;
#pragma unroll
            for (int u = 0; u < 4; ++u) sum += acc[s][u][r] * acc[s][u][r];
#pragma unroll
            for (int off = 8; off >= 1; off >>= 1) sum += __shfl_xor(sum, off);
            psq[s][r] = sum;
        }
    if (li == 0) {
#pragma unroll
        for (int s = 0; s < 4; ++s)
#pragma unroll
            for (int r = 0; r < 4; ++r) ls[wv][s * 16 + lk * 4 + r] = psq[s][r];
    }
    __syncthreads();
    if (threadIdx.x < 64) {
        const int tt = threadIdx.x;
        const float tot = ls[0][tt] + ls[1][tt] + ls[2][tt] + ls[3][tt];
        ls2[tt] = 1.f / fmaxf(sqrtf(tot), EPS);
    }
    __syncthreads();
    float scl[4][4];
#pragma unroll
    for (int s = 0; s < 4; ++s)
#pragma unroll
        for (int r = 0; r < 4; ++r) scl[s][r] = ls2[s * 16 + lk * 4 + r];
    float* ob = out + (size_t)b * C * N;
#pragma unroll
    for (int s = 0; s < 4; ++s)
#pragma unroll
        for (int u = 0; u < 4; ++u) {
            f32x4 q;
#pragma unroll
            for (int r = 0; r < 4; ++r) q[r] = acc[s][u][r] * scl[s][r];
            *(f32x4*)(ob + (size_t)(cb + u * 16 + li) * N + n0 + s * 16 + lk * 4) = q;
        }
}

// ---------------------------------------------------------------------------
// K5 / K6: losses.
// ---------------------------------------------------------------------------
__global__ __launch_bounds__(256) void k5_dis(const unsigned short* __restrict__ proto_bf,
                                              const float* __restrict__ p2,
                                              float* __restrict__ dparts) {
    const int q = blockIdx.x;
    const int b = blockIdx.y;
    const unsigned short* pr = proto_bf + (size_t)b * M * C;
    __shared__ float pl[M * C];
    for (int idx = threadIdx.x; idx < M * C; idx += 256) {
        int m = idx >> 8, c = idx & 255;
        pl[m * 256 + (c ^ (m & 31))] = bf2f(pr[idx]);
    }
    __syncthreads();
    float sum = 0.f;
    for (int k = 0; k < 2; ++k) {
        const int pair = q * 512 + k * 256 + threadIdx.x;
        const int i = pair >> 6, j = pair & 63;
        if (j > i) {
            float g = 0.f;
#pragma unroll 8
            for (int c = 0; c < C; ++c)
                g += pl[i * 256 + (c ^ (i & 31))] * pl[j * 256 + (c ^ (j & 31))];
            const float d = 1.f - (p2[b * M + i] + p2[b * M + j] - 2.f * g);
            sum += fmaxf(d, 0.f);
        }
    }
#pragma unroll
    for (int off = 32; off >= 1; off >>= 1) sum += __shfl_xor(sum, off);
    __shared__ float red[4];
    const int wave = threadIdx.x >> 6, lane = threadIdx.x & 63;
    if (lane == 0) red[wave] = sum;
    __syncthreads();
    if (threadIdx.x == 0) dparts[b * 8 + q] = red[0] + red[1] + red[2] + red[3];
}

__global__ __launch_bounds__(256) void k6_final(const float* __restrict__ cparts, int ncp,
                                                const float* __restrict__ dparts,
                                                float* __restrict__ losses) {
    const int t = threadIdx.x;
    float cs = 0.f;
    for (int i = t; i < ncp; i += 256) cs += cparts[i];
    float ds = dparts[t];
#pragma unroll
    for (int off = 32; off >= 1; off >>= 1) {
        cs += __shfl_xor(cs, off);
        ds += __shfl_xor(ds, off);
    }
    __shared__ float rc[4], rd[4];
    const int wave = t >> 6, lane = t & 63;
    if (lane == 0) { rc[wave] = cs; rd[wave] = ds; }
    __syncthreads();
    if (t == 0) {
        const float ctot = rc[0] + rc[1] + rc[2] + rc[3];
        const float dtot = rd[0] + rd[1] + rd[2] + rd[3];
        losses[0] = ctot / ((float)B * (float)N * (float)C);
        losses[1] = dtot * (2.f / (float)(M * (M - 1))) / (float)B;
    }
}

extern "C" void kernel_launch(void* const* d_in, const int* in_sizes, int n_in,
                              void* d_out, int out_size, void* d_ws, size_t ws_size,
                              hipStream_t stream) {
    const float* x = (const float*)d_in[0];
    const float* Wf = (const float*)d_in[1];
    float* out = (float*)d_out;
    float* wsf = (float*)d_ws;
    float* losses = out + (size_t)B * C * N;

    // Proven layout (r3/r4/r7): xbt in d_out (dead before k4b overwrites), rest in ws.
    unsigned short* xbt = (unsigned short*)d_out;
    unsigned short* Sbf = (unsigned short*)wsf;
    float* parts = wsf;
    unsigned short* Pbf = (unsigned short*)(wsf + 4194304);
    unsigned short* pnm = Pbf;
    float* xsq = wsf + 8388608;
    unsigned short* proto_bf = (unsigned short*)(wsf + 8519680);
    unsigned short* protoT_bf = (unsigned short*)(wsf + 8781824);
    float* p2 = wsf + 9052160;
    float* cparts = wsf + 9054208;
    float* dparts = wsf + 9054720;

    k01<<<dim3(N / 64, B), 256, 0, stream>>>(x, Wf, xbt, Sbf, xsq);
    k2_softmax_n<<<dim3(M, B), 256, 0, stream>>>(Sbf, Pbf);
    k3_mfma<<<dim3(8, 2, B), 256, 0, stream>>>(x, Pbf, parts);
    k3b_reduce<<<dim3(8, B), 256, 0, stream>>>(parts, proto_bf, protoT_bf, p2);
    k4_score<<<dim3(N / 256, B), 256, 0, stream>>>(proto_bf, xbt, p2, xsq, pnm, cparts);
    k4b_mfma<<<dim3(N / 64, B), 256, 0, stream>>>(pnm, protoT_bf, out);
    k5_dis<<<dim3(8, B), 256, 0, stream>>>(proto_bf, p2, dparts);
    k6_final<<<1, 256, 0, stream>>>(cparts, B * 16, dparts, losses);
}

// Round 12
// 173.410 us; speedup vs baseline: 1.1867x; 1.0271x over previous
//
#include <hip/hip_runtime.h>
#include <math.h>

#define B 32
#define C 256
#define M 64
#define N 4096  // H*W

typedef __attribute__((ext_vector_type(8))) short s16x8;
typedef __attribute__((ext_vector_type(8))) __bf16 bf16x8;
typedef __attribute__((ext_vector_type(4))) __bf16 bf16x4;
typedef __attribute__((ext_vector_type(4))) float f32x4;
typedef __attribute__((ext_vector_type(4))) unsigned short u16x4;
typedef __attribute__((ext_vector_type(8))) unsigned short u16x8;

static constexpr float EPS = 1e-12f;

__device__ __forceinline__ float bf2f(unsigned short h) {
    return __uint_as_float((unsigned)h << 16);
}
__device__ __forceinline__ f32x4 MFMA(s16x8 a, s16x8 b, f32x4 c) {
    return __builtin_amdgcn_mfma_f32_16x16x32_bf16(
        __builtin_bit_cast(bf16x8, a), __builtin_bit_cast(bf16x8, b), c, 0, 0, 0);
}
__device__ __forceinline__ s16x8 cvt8(const f32x4 a, const f32x4 b) {
    bf16x8 h;
    h[0] = (__bf16)a[0]; h[1] = (__bf16)a[1]; h[2] = (__bf16)a[2]; h[3] = (__bf16)a[3];
    h[4] = (__bf16)b[0]; h[5] = (__bf16)b[1]; h[6] = (__bf16)b[2]; h[7] = (__bf16)b[3];
    return __builtin_bit_cast(s16x8, h);
}
// LDS column swizzle for the [n][c] bf16 tile (halfword units, flips bits 3-5 of c)
__device__ __forceinline__ int swz(int n) {
    return (((n >> 2) & 3) | ((n & 1) << 2)) << 3;
}

// ---------------------------------------------------------------------------
// K01: fused convert + transpose + logits (r7-proven, 74.8us).
// ---------------------------------------------------------------------------
__global__ __launch_bounds__(256) void k01(const float* __restrict__ x,
                                           const float* __restrict__ Wf,
                                           unsigned short* __restrict__ xbt,
                                           unsigned short* __restrict__ Sb,
                                           float* __restrict__ xsq) {
    const int nb = blockIdx.x, b = blockIdx.y;
    const int t = threadIdx.x;
    __shared__ unsigned short tsT[64 * 256];
    __shared__ float xred[16][68];
    // ---- phase A: load 4c x 4n register blocks, cvt, stage to LDS ----
    const int nq = t & 15, cq = t >> 4;
    float part[4] = {0.f, 0.f, 0.f, 0.f};
    const float* xrow = x + (size_t)b * C * N + (size_t)nb * 64 + 4 * nq;
#pragma unroll
    for (int step = 0; step < 4; ++step) {
        const int c0 = cq * 4 + step * 64;
        f32x4 q[4];
#pragma unroll
        for (int i = 0; i < 4; ++i) q[i] = *(const f32x4*)(xrow + (size_t)(c0 + i) * N);
#pragma unroll
        for (int k = 0; k < 4; ++k) {
            const int n = 4 * nq + k;
            bf16x4 hb;
#pragma unroll
            for (int i = 0; i < 4; ++i) {
                part[k] += q[i][k] * q[i][k];
                hb[i] = (__bf16)q[i][k];
            }
            *(u16x4*)(&tsT[n * 256 + (c0 ^ swz(n))]) = __builtin_bit_cast(u16x4, hb);
        }
    }
#pragma unroll
    for (int k = 0; k < 4; ++k) xred[cq][4 * nq + k] = part[k];
    __syncthreads();
    if (t < 64) {
        float s = 0.f;
#pragma unroll
        for (int j = 0; j < 16; ++j) s += xred[j][t];
        xsq[(size_t)b * N + nb * 64 + t] = s;
    }
    // ---- phase B1: xbt coalesced write ----
    {
        const int l = t & 31, nh = t >> 5;
#pragma unroll
        for (int j = 0; j < 8; ++j) {
            const int n = nh + 8 * j;
            const int c0 = l * 8;
            const u16x8 v = *(const u16x8*)(&tsT[n * 256 + (c0 ^ swz(n))]);
            *(u16x8*)(xbt + ((size_t)b * N + nb * 64 + n) * C + c0) = v;
        }
    }
    // ---- phase B2: logits MFMA (W f32 -> bf16 in-reg) ----
    const int wv = t >> 6, lane = t & 63, li = lane & 15, lk = lane >> 4;
    const f32x4 zv = {0.f, 0.f, 0.f, 0.f};
    f32x4 acc[4] = {zv, zv, zv, zv};
    const float* wr = Wf + (size_t)(wv * 16 + li) * C + lk * 8;
#pragma unroll
    for (int c0 = 0; c0 < C; c0 += 32) {
        const s16x8 bfrag = cvt8(*(const f32x4*)(wr + c0), *(const f32x4*)(wr + c0 + 4));
#pragma unroll
        for (int s = 0; s < 4; ++s) {
            const int n = s * 16 + li;
            const s16x8 a = *(const s16x8*)(&tsT[n * 256 + ((lk * 8 + c0) ^ swz(n))]);
            acc[s] = MFMA(a, bfrag, acc[s]);
        }
    }
    unsigned short* Srow = Sb + ((size_t)b * M + wv * 16 + li) * N + nb * 64;
#pragma unroll
    for (int s = 0; s < 4; ++s) {
        bf16x4 h;
#pragma unroll
        for (int r = 0; r < 4; ++r) h[r] = (__bf16)acc[s][r];
        *(u16x4*)(Srow + s * 16 + lk * 4) = __builtin_bit_cast(u16x4, h);
    }
}

// ---------------------------------------------------------------------------
// K2: softmax over n per (b,m); bf16 in -> bf16 out.
// ---------------------------------------------------------------------------
__global__ __launch_bounds__(256) void k2_softmax_n(const unsigned short* __restrict__ Sb,
                                                    unsigned short* __restrict__ Pb) {
    const int m = blockIdx.x, b = blockIdx.y;
    const unsigned short* col = Sb + ((size_t)b * M + m) * N;
    unsigned short* po = Pb + ((size_t)b * M + m) * N;
    const int t = threadIdx.x;
    float v[16];
    const u16x8 h0 = *(const u16x8*)(col + t * 16);
    const u16x8 h1 = *(const u16x8*)(col + t * 16 + 8);
#pragma unroll
    for (int i = 0; i < 8; ++i) v[i] = bf2f(h0[i]);
#pragma unroll
    for (int i = 0; i < 8; ++i) v[8 + i] = bf2f(h1[i]);
    float mx = -INFINITY;
#pragma unroll
    for (int i = 0; i < 16; ++i) mx = fmaxf(mx, v[i]);
#pragma unroll
    for (int off = 32; off >= 1; off >>= 1) mx = fmaxf(mx, __shfl_xor(mx, off));
    __shared__ float redm[4], reds[4];
    const int wave = t >> 6, lane = t & 63;
    if (lane == 0) redm[wave] = mx;
    __syncthreads();
    mx = fmaxf(fmaxf(redm[0], redm[1]), fmaxf(redm[2], redm[3]));
    float s = 0.f;
#pragma unroll
    for (int i = 0; i < 16; ++i) {
        v[i] = __expf(v[i] - mx);
        s += v[i];
    }
#pragma unroll
    for (int off = 32; off >= 1; off >>= 1) s += __shfl_xor(s, off);
    if (lane == 0) reds[wave] = s;
    __syncthreads();
    s = reds[0] + reds[1] + reds[2] + reds[3];
    const float inv = 1.f / s;
    bf16x8 o0, o1;
#pragma unroll
    for (int i = 0; i < 8; ++i) o0[i] = (__bf16)(v[i] * inv);
#pragma unroll
    for (int i = 0; i < 8; ++i) o1[i] = (__bf16)(v[8 + i] * inv);
    *(u16x8*)(po + t * 16) = __builtin_bit_cast(u16x8, o0);
    *(u16x8*)(po + t * 16 + 8) = __builtin_bit_cast(u16x8, o1);
}

// ---------------------------------------------------------------------------
// K3: proto partials parts[b][ck][m][c] over 512-n chunks (r7-proven form).
// ---------------------------------------------------------------------------
__global__ __launch_bounds__(256) void k3_mfma(const float* __restrict__ x,
                                               const unsigned short* __restrict__ Pb,
                                               float* __restrict__ parts) {
    const int ck = blockIdx.x, b = blockIdx.y;
    const int wv = threadIdx.x >> 6, lane = threadIdx.x & 63;
    const int li = lane & 15, lk = lane >> 4;
    const int c0w = wv * 64;
    const int nb = ck * 512;
    const f32x4 zv = {0.f, 0.f, 0.f, 0.f};
    f32x4 acc[4][4];
#pragma unroll
    for (int s = 0; s < 4; ++s)
#pragma unroll
        for (int u = 0; u < 4; ++u) acc[s][u] = zv;
    const float* ar = x + ((size_t)b * C + c0w + li) * N + nb + lk * 8;
    const unsigned short* br = Pb + ((size_t)b * M + li) * N + nb + lk * 8;
#pragma unroll 4
    for (int n0 = 0; n0 < 512; n0 += 32) {
        s16x8 af[4], bf_[4];
#pragma unroll
        for (int s = 0; s < 4; ++s) {
            const float* p = ar + (size_t)(s * 16) * N + n0;
            af[s] = cvt8(*(const f32x4*)p, *(const f32x4*)(p + 4));
        }
#pragma unroll
        for (int u = 0; u < 4; ++u) bf_[u] = *(const s16x8*)(br + (size_t)(u * 16) * N + n0);
#pragma unroll
        for (int s = 0; s < 4; ++s)
#pragma unroll
            for (int u = 0; u < 4; ++u) acc[s][u] = MFMA(af[s], bf_[u], acc[s][u]);
    }
    float* pp = parts + ((size_t)b * 8 + ck) * M * C;
#pragma unroll
    for (int s = 0; s < 4; ++s)
#pragma unroll
        for (int u = 0; u < 4; ++u)
            *(f32x4*)(pp + (size_t)(u * 16 + li) * C + c0w + s * 16 + lk * 4) = acc[s][u];
}

// ---------------------------------------------------------------------------
// K3b: reduce 8 chunks -> l2norm -> proto_bf [m][c], protoT_bf [c][m], p2.
// ---------------------------------------------------------------------------
__global__ __launch_bounds__(256) void k3b_reduce(const float* __restrict__ parts,
                                                  unsigned short* __restrict__ proto_bf,
                                                  unsigned short* __restrict__ protoT_bf,
                                                  float* __restrict__ p2) {
    const int mb = blockIdx.x, b = blockIdx.y;
    const int t = threadIdx.x;
    const int ml = t >> 5, cl = t & 31;
    const int m = mb * 8 + ml;
    const int c0 = cl * 8;
    float v[8] = {0.f, 0.f, 0.f, 0.f, 0.f, 0.f, 0.f, 0.f};
    const float* pbase = parts + (size_t)b * 8 * M * C + (size_t)m * C + c0;
#pragma unroll
    for (int ck = 0; ck < 8; ++ck) {
        const f32x4 q0 = *(const f32x4*)(pbase + (size_t)ck * M * C);
        const f32x4 q1 = *(const f32x4*)(pbase + (size_t)ck * M * C + 4);
#pragma unroll
        for (int j = 0; j < 4; ++j) { v[j] += q0[j]; v[4 + j] += q1[j]; }
    }
    float sq = 0.f;
#pragma unroll
    for (int j = 0; j < 8; ++j) sq += v[j] * v[j];
#pragma unroll
    for (int off = 16; off >= 1; off >>= 1) sq += __shfl_xor(sq, off);
    const float denom = fmaxf(sqrtf(sq), EPS);
    const float scale = 1.f / denom;
    if (cl == 0) p2[b * M + m] = sq / (denom * denom);
    bf16x8 h;
#pragma unroll
    for (int j = 0; j < 8; ++j) h[j] = (__bf16)(v[j] * scale);
    const u16x8 hu = __builtin_bit_cast(u16x8, h);
    *(u16x8*)(proto_bf + ((size_t)b * M + m) * C + c0) = hu;
#pragma unroll
    for (int j = 0; j < 8; ++j)
        protoT_bf[((size_t)b * C + c0 + j) * M + m] = hu[j];
}

// ---------------------------------------------------------------------------
// K4: score + softmax-m (unnormalized; 1/sum cancels in L2-norm) + compact
// partials -> pnm bf16 [b][n][m].
// ---------------------------------------------------------------------------
__global__ __launch_bounds__(256) void k4_score(const unsigned short* __restrict__ proto_bf,
                                                const unsigned short* __restrict__ xbt,
                                                const float* __restrict__ p2,
                                                const float* __restrict__ xsq,
                                                unsigned short* __restrict__ pnm,
                                                float* __restrict__ cparts) {
    const int b = blockIdx.y;
    const int wv = threadIdx.x >> 6, lane = threadIdx.x & 63;
    const int li = lane & 15, lk = lane >> 4;
    const int nbase = blockIdx.x * 256 + wv * 64;
    const f32x4 zv = {0.f, 0.f, 0.f, 0.f};
    f32x4 acc[4][4];
#pragma unroll
    for (int s = 0; s < 4; ++s)
#pragma unroll
        for (int u = 0; u < 4; ++u) acc[s][u] = zv;
    const unsigned short* ar = proto_bf + ((size_t)b * M + li) * C + lk * 8;
    const unsigned short* br = xbt + ((size_t)b * N + nbase + li) * C + lk * 8;
#pragma unroll
    for (int c0 = 0; c0 < C; c0 += 32) {
        s16x8 af[4], bf_[4];
#pragma unroll
        for (int s = 0; s < 4; ++s) af[s] = *(const s16x8*)(ar + (size_t)(s * 16) * C + c0);
#pragma unroll
        for (int u = 0; u < 4; ++u) bf_[u] = *(const s16x8*)(br + (size_t)(u * 16) * C + c0);
#pragma unroll
        for (int s = 0; s < 4; ++s)
#pragma unroll
            for (int u = 0; u < 4; ++u) acc[s][u] = MFMA(af[s], bf_[u], acc[s][u]);
    }
    float csum = 0.f;
#pragma unroll
    for (int u = 0; u < 4; ++u) {
        const int n = nbase + u * 16 + li;
        float vmax = -INFINITY;
#pragma unroll
        for (int s = 0; s < 4; ++s)
#pragma unroll
            for (int r = 0; r < 4; ++r) vmax = fmaxf(vmax, acc[s][u][r]);
        vmax = fmaxf(vmax, __shfl_xor(vmax, 16));
        vmax = fmaxf(vmax, __shfl_xor(vmax, 32));
        int t1 = 1 << 30;
#pragma unroll
        for (int s = 0; s < 4; ++s)
#pragma unroll
            for (int r = 0; r < 4; ++r)
                if (acc[s][u][r] == vmax) t1 = min(t1, s * 16 + lk * 4 + r);
        t1 = min(t1, __shfl_xor(t1, 16));
        t1 = min(t1, __shfl_xor(t1, 32));
        unsigned short* prow = pnm + ((size_t)b * N + n) * M;
#pragma unroll
        for (int s = 0; s < 4; ++s) {
            bf16x4 h;
#pragma unroll
            for (int r = 0; r < 4; ++r) h[r] = (__bf16)__expf(acc[s][u][r] - vmax);
            *(u16x4*)(prow + s * 16 + lk * 4) = __builtin_bit_cast(u16x4, h);
        }
        if (lk == 0) csum += xsq[(size_t)b * N + n] - 2.f * vmax + p2[b * M + t1];
    }
#pragma unroll
    for (int off = 32; off >= 1; off >>= 1) csum += __shfl_xor(csum, off);
    __shared__ float red[4];
    if (lane == 0) red[wv] = csum;
    __syncthreads();
    if (threadIdx.x == 0)
        cparts[b * 16 + blockIdx.x] = red[0] + red[1] + red[2] + red[3];
}

// ---------------------------------------------------------------------------
// K4b: out = l2norm_c(sum_m p[n][m]*protoT[c][m]).
// ---------------------------------------------------------------------------
__global__ __launch_bounds__(256) void k4b_mfma(const unsigned short* __restrict__ pnm,
                                                const unsigned short* __restrict__ protoT_bf,
                                                float* __restrict__ out) {
    const int b = blockIdx.y;
    const int wv = threadIdx.x >> 6, lane = threadIdx.x & 63;
    const int li = lane & 15, lk = lane >> 4;
    const int n0 = blockIdx.x * 64;
    const int cb = wv * 64;
    const f32x4 zv = {0.f, 0.f, 0.f, 0.f};
    f32x4 acc[4][4];
#pragma unroll
    for (int s = 0; s < 4; ++s)
#pragma unroll
        for (int u = 0; u < 4; ++u) acc[s][u] = zv;
    const unsigned short* ar = pnm + ((size_t)b * N + n0 + li) * M + lk * 8;
    const unsigned short* br = protoT_bf + ((size_t)b * C + cb + li) * M + lk * 8;
#pragma unroll
    for (int m0 = 0; m0 < M; m0 += 32) {
        s16x8 af[4], bf_[4];
#pragma unroll
        for (int s = 0; s < 4; ++s) af[s] = *(const s16x8*)(ar + (size_t)(s * 16) * M + m0);
#pragma unroll
        for (int u = 0; u < 4; ++u) bf_[u] = *(const s16x8*)(br + (size_t)(u * 16) * M + m0);
#pragma unroll
        for (int s = 0; s < 4; ++s)
#pragma unroll
            for (int u = 0; u < 4; ++u) acc[s][u] = MFMA(af[s], bf_[u], acc[s][u]);
    }
    __shared__ float ls[4][64];
    __shared__ float ls2[64];
    float psq[4][4];
#pragma unroll
    for (int s = 0; s < 4; ++s)
#pragma unroll
        for (int r = 0; r < 4; ++r) {
            float sum = 0.f;
#pragma unroll
            for (int u = 0; u < 4; ++u) sum += acc[s][u][r] * acc[s][u][r];
#pragma unroll
            for (int off = 8; off >= 1; off >>= 1) sum += __shfl_xor(sum, off);
            psq[s][r] = sum;
        }
    if (li == 0) {
#pragma unroll
        for (int s = 0; s < 4; ++s)
#pragma unroll
            for (int r = 0; r < 4; ++r) ls[wv][s * 16 + lk * 4 + r] = psq[s][r];
    }
    __syncthreads();
    if (threadIdx.x < 64) {
        const int tt = threadIdx.x;
        const float tot = ls[0][tt] + ls[1][tt] + ls[2][tt] + ls[3][tt];
        ls2[tt] = 1.f / fmaxf(sqrtf(tot), EPS);
    }
    __syncthreads();
    float scl[4][4];
#pragma unroll
    for (int s = 0; s < 4; ++s)
#pragma unroll
        for (int r = 0; r < 4; ++r) scl[s][r] = ls2[s * 16 + lk * 4 + r];
    float* ob = out + (size_t)b * C * N;
#pragma unroll
    for (int s = 0; s < 4; ++s)
#pragma unroll
        for (int u = 0; u < 4; ++u) {
            f32x4 q;
#pragma unroll
            for (int r = 0; r < 4; ++r) q[r] = acc[s][u][r] * scl[s][r];
            *(f32x4*)(ob + (size_t)(cb + u * 16 + li) * N + n0 + s * 16 + lk * 4) = q;
        }
}

// ---------------------------------------------------------------------------
// K5 / K6: losses.
// ---------------------------------------------------------------------------
__global__ __launch_bounds__(256) void k5_dis(const unsigned short* __restrict__ proto_bf,
                                              const float* __restrict__ p2,
                                              float* __restrict__ dparts) {
    const int q = blockIdx.x;
    const int b = blockIdx.y;
    const unsigned short* pr = proto_bf + (size_t)b * M * C;
    __shared__ float pl[M * C];
    for (int idx = threadIdx.x; idx < M * C; idx += 256) {
        int m = idx >> 8, c = idx & 255;
        pl[m * 256 + (c ^ (m & 31))] = bf2f(pr[idx]);
    }
    __syncthreads();
    float sum = 0.f;
    for (int k = 0; k < 2; ++k) {
        const int pair = q * 512 + k * 256 + threadIdx.x;
        const int i = pair >> 6, j = pair & 63;
        if (j > i) {
            float g = 0.f;
#pragma unroll 8
            for (int c = 0; c < C; ++c)
                g += pl[i * 256 + (c ^ (i & 31))] * pl[j * 256 + (c ^ (j & 31))];
            const float d = 1.f - (p2[b * M + i] + p2[b * M + j] - 2.f * g);
            sum += fmaxf(d, 0.f);
        }
    }
#pragma unroll
    for (int off = 32; off >= 1; off >>= 1) sum += __shfl_xor(sum, off);
    __shared__ float red[4];
    const int wave = threadIdx.x >> 6, lane = threadIdx.x & 63;
    if (lane == 0) red[wave] = sum;
    __syncthreads();
    if (threadIdx.x == 0) dparts[b * 8 + q] = red[0] + red[1] + red[2] + red[3];
}

__global__ __launch_bounds__(256) void k6_final(const float* __restrict__ cparts, int ncp,
                                                const float* __restrict__ dparts,
                                                float* __restrict__ losses) {
    const int t = threadIdx.x;
    float cs = 0.f;
    for (int i = t; i < ncp; i += 256) cs += cparts[i];
    float ds = dparts[t];
#pragma unroll
    for (int off = 32; off >= 1; off >>= 1) {
        cs += __shfl_xor(cs, off);
        ds += __shfl_xor(ds, off);
    }
    __shared__ float rc[4], rd[4];
    const int wave = t >> 6, lane = t & 63;
    if (lane == 0) { rc[wave] = cs; rd[wave] = ds; }
    __syncthreads();
    if (t == 0) {
        const float ctot = rc[0] + rc[1] + rc[2] + rc[3];
        const float dtot = rd[0] + rd[1] + rd[2] + rd[3];
        losses[0] = ctot / ((float)B * (float)N * (float)C);
        losses[1] = dtot * (2.f / (float)(M * (M - 1))) / (float)B;
    }
}

extern "C" void kernel_launch(void* const* d_in, const int* in_sizes, int n_in,
                              void* d_out, int out_size, void* d_ws, size_t ws_size,
                              hipStream_t stream) {
    const float* x = (const float*)d_in[0];
    const float* Wf = (const float*)d_in[1];
    float* out = (float*)d_out;
    float* wsf = (float*)d_ws;
    float* losses = out + (size_t)B * C * N;

    // Proven layout (r3/r4/r7): xbt in d_out (dead before k4b overwrites), rest in ws.
    unsigned short* xbt = (unsigned short*)d_out;
    unsigned short* Sbf = (unsigned short*)wsf;
    float* parts = wsf;
    unsigned short* Pbf = (unsigned short*)(wsf + 4194304);
    unsigned short* pnm = Pbf;
    float* xsq = wsf + 8388608;
    unsigned short* proto_bf = (unsigned short*)(wsf + 8519680);
    unsigned short* protoT_bf = (unsigned short*)(wsf + 8781824);
    float* p2 = wsf + 9052160;
    float* cparts = wsf + 9054208;
    float* dparts = wsf + 9054720;

    k01<<<dim3(N / 64, B), 256, 0, stream>>>(x, Wf, xbt, Sbf, xsq);
    k2_softmax_n<<<dim3(M, B), 256, 0, stream>>>(Sbf, Pbf);
    k3_mfma<<<dim3(8, B), 256, 0, stream>>>(x, Pbf, parts);
    k3b_reduce<<<dim3(8, B), 256, 0, stream>>>(parts, proto_bf, protoT_bf, p2);
    k4_score<<<dim3(N / 256, B), 256, 0, stream>>>(proto_bf, xbt, p2, xsq, pnm, cparts);
    k4b_mfma<<<dim3(N / 64, B), 256, 0, stream>>>(pnm, protoT_bf, out);
    k5_dis<<<dim3(8, B), 256, 0, stream>>>(proto_bf, p2, dparts);
    k6_final<<<1, 256, 0, stream>>>(cparts, B * 16, dparts, losses);
}